// Round 4
// baseline (8447.139 us; speedup 1.0000x reference)
//
#include <hip/hip_runtime.h>
#include <hip/hip_fp16.h>
#include <cmath>

// ---------------------------------------------------------------------------
// LMU fused recurrence.  One 128x1536 @ 1536x1536 GEMM per step (tanh on
// first 1024 cols, linear on last 512), x-dependent rank-1 bias.
// r22 = r21 (dual-pipeline) + epilogue row-mapping FIX.
//   r21 bug: C-fragment valid rows are 0-7 (quads 0,1) for BOTH pipelines
//   (A row index = l16, each pipeline loads its 8 rows into A rows 0-7).
//   r21's epilogue picked quads 2,3 for pipeline 1 -> stored the ZERO rows
//   into batch rows +8..15 (absmax 0.33).  Fix: my_rows = (quad < 2),
//   b = isl*16 + p*8 + quad*4 + r, same offset for inputs.
// Dual-pipeline design (unchanged from r21): the 128 batch rows are
// INDEPENDENT recurrences; split each island into two independent 8-row
// pipelines (A: rows +0..8, B: rows +8..16) sharing the W slices read-only.
// While pipeline A sits in its serial sync/latency chain, B's waves compute
// on the same SIMDs, and vice versa.  Evidence the chain is the wall:
// r19 (2x waves, same pipeline) moved NO counter; r20 (per-wave producer
// gating) gained only 3% -- lockstep has no skew to exploit; only a second
// independent time-offset chain can fill the idle.
//   - 512 thr = 8 waves: wv>>2 = pipeline, wv&3 = role within pipeline
//     (K-split 12 kt each, exactly r18's 4-wave structure per pipeline).
//   - NO __syncthreads in the loop (would couple pipelines).  Per-pipeline
//     LDS-atomic barriers (monotonic epoch counters, lane0 arrive, all-lane
//     spin on broadcast atomic load).  K-split reduce is two-phase (w01
//     write, w23 add) into red[pipe][2][3][64]; LDS = 147456+12288 <= 160K.
//   - A-frag lanes l16>=8 exec-masked to zero: MFMA tiles half-empty
//     (M=16, 8 real rows).  MFMA was 15% busy -> affordable trade.
//   - Per-pipeline per-CU flags, r20 poll mechanism verbatim.  Planes are
//     row-disjoint between pipelines; drift<=1 proof holds per pipeline.
//   Locked-in lessons kept: flag words touched by atomic RMWs ONLY (r16
//   races; r12 InstCombine demotes fetch_add(0) to a load; r14 sc0 loads
//   served stale from L1).  Register budget: 2 waves/SIMD -> V+A <= 256;
//   W_lo = 144 AGPR, loop shaped like r19 (92 VGPR there).
// Design otherwise = r13/r18:
//   - XCD-local islands (s_getreg XCC_ID + rank registration, 1 WG/CU).
//   - W_hi slice (147 KB) in LDS; plain L2-local state loads/stores;
//     per-wave CU-local L1 buffer_inv after flag wait.
// Precision: EXACT r3-r13 verified scheme (absmax 4.9e-4): f16 hi/lo state
// and weights (lo x2048), fp32 MFMA accumulate, 3 products.
// ---------------------------------------------------------------------------

typedef _Float16 half8 __attribute__((ext_vector_type(8)));
typedef float floatx4 __attribute__((ext_vector_type(4)));

#define NSTATE   1536
#define BATCH    128
#define TSTEPS   784
#define KTILES   48
#define ISL_WGS  32                  // WGs per island (= CUs per XCD)
#define SLICE_H8 9216                // half8 per 48-col weight slice (48*3*64)
#define LO_SCALE 2048.0f
#define LO_INV   (1.0f / 2048.0f)
#define PIPES    2

__device__ __align__(16) _Float16 g_Whi[NSTATE * NSTATE];
__device__ __align__(16) _Float16 g_Wlo[NSTATE * NSTATE];
__device__ float    g_wb[NSTATE];
__device__ float    g_WmA[1024 * 512];
__device__ float    g_WmB[1024];
__device__ __align__(16) _Float16 g_Shi[2 * BATCH * NSTATE];
__device__ __align__(16) _Float16 g_Slo[2 * BATCH * NSTATE];
// [512 + xcd*64]: registration counters (RMW-only)
__device__ unsigned g_bar[1024];
// per-pipeline per-producer dataflow flags: word ((p*8+isl)*32 + sl)*64,
// 256B apart (own L2 line each).  RMW-only.  Value = completed store-epochs.
__device__ unsigned g_flags[PIPES * 8 * 32 * 64];

// Forced local-L2 atomic RMW poll (returns pre-add value).  InstCombine
// cannot demote this to a (stale-L1-cacheable) load -- r12/r14 lessons.
__device__ __forceinline__ unsigned poll_rmw(unsigned* p) {
    unsigned old;
    asm volatile("global_atomic_add %0, %1, %2, off sc0\n\ts_waitcnt vmcnt(0)"
                 : "=&v"(old)
                 : "v"(p), "v"(0u)
                 : "memory");
    return old;
}

// Per-pipeline LDS barrier primitives: monotonic epoch counters, never
// reset.  lane0 arrives (RELEASE orders the wave's prior LDS/global ops);
// all lanes spin on a broadcast atomic load (LDS is CU-coherent -- no r14
// staleness hazard here).
__device__ __forceinline__ void lds_arrive(unsigned* c) {
    if ((threadIdx.x & 63) == 0)
        __hip_atomic_fetch_add(c, 1u, __ATOMIC_RELEASE,
                               __HIP_MEMORY_SCOPE_WORKGROUP);
}
__device__ __forceinline__ void lds_wait(unsigned* c, unsigned tgt) {
    int spin = 0;
    while (__hip_atomic_load(c, __ATOMIC_ACQUIRE,
                             __HIP_MEMORY_SCOPE_WORKGROUP) < tgt) {
        if (++spin > (1 << 20)) break;  // deadman: no hang
    }
}

// Branch-free tanh: 1 - 2/(e^{2x}+1).  __expf -> v_exp_f32.  Exact limits:
// e=inf -> 1, e=0 -> -1.  |err| ~1e-7 (absmax margin is 20x).
__device__ __forceinline__ float fast_tanh(float x) {
    float e = __expf(2.f * x);
    return 1.f - 2.f / (e + 1.f);
}

// W_mB[i] = sum_c W_m[i,c] * BT[c]
__global__ void prep_wmb(const float* __restrict__ Wm, const float* __restrict__ BT) {
    int row  = blockIdx.x * 4 + (threadIdx.x >> 6);
    int lane = threadIdx.x & 63;
    float s = 0.f;
    for (int c = lane; c < 512; c += 64) s += Wm[row * 512 + c] * BT[c];
    for (int o = 32; o; o >>= 1) s += __shfl_down(s, o);
    if (lane == 0) g_WmB[row] = s;
}

// W_mA = W_m @ (I + AT)
__global__ void prep_wma(const float* __restrict__ Wm, const float* __restrict__ AT) {
    __shared__ float As[32][33], Bs[32][33];
    int d0 = blockIdx.x * 32, i0 = blockIdx.y * 32;
    int tx = threadIdx.x & 31, ty = threadIdx.x >> 5;
    float acc[4];
#pragma unroll
    for (int r = 0; r < 4; ++r) acc[r] = Wm[(i0 + ty + 8 * r) * 512 + d0 + tx];
    for (int c0 = 0; c0 < 512; c0 += 32) {
#pragma unroll
        for (int r = 0; r < 4; ++r) {
            As[ty + 8 * r][tx] = Wm[(i0 + ty + 8 * r) * 512 + c0 + tx];
            Bs[ty + 8 * r][tx] = AT[(c0 + ty + 8 * r) * 512 + d0 + tx];
        }
        __syncthreads();
#pragma unroll
        for (int c = 0; c < 32; ++c)
#pragma unroll
            for (int r = 0; r < 4; ++r) acc[r] += As[ty + 8 * r][c] * Bs[c][tx];
        __syncthreads();
    }
#pragma unroll
    for (int r = 0; r < 4; ++r) g_WmA[(i0 + ty + 8 * r) * 512 + d0 + tx] = acc[r];
}

// Build W_full, f16 hi/lo (lo x2048), in slice-major fragment order:
// storage s = (((sl*48 + kt)*3 + nt)*64 + lane)*8 + j
//   n = sl*48 + nt*16 + (lane&15),  k = kt*32 + ((lane>>4)&3)*8 + j
__global__ void prep_wfull(const float* __restrict__ Wh, const float* __restrict__ AT,
                           const float* __restrict__ BT, const float* __restrict__ eh,
                           const float* __restrict__ em, const float* __restrict__ ex,
                           const float* __restrict__ Wx) {
    int s = blockIdx.x * 256 + threadIdx.x;     // [0, 1536*1536)
    int j8 = s & 7;
    int u = s >> 3;
    int lane = u & 63;
    u >>= 6;                                    // [0, 4608)
    int nt = u % 3; u /= 3;
    int kt = u % 48;
    int sl = u / 48;
    int n = sl * 48 + nt * 16 + (lane & 15);
    int k = kt * 32 + ((lane >> 4) & 3) * 8 + j8;

    float w;
    if (n < 1024) {
        if (k < 1024) w = Wh[n * 1024 + k] + g_WmB[n] * eh[k];
        else          w = g_WmA[n * 512 + (k - 1024)] + g_WmB[n] * em[k - 1024];
    } else {
        int c = n - 1024;
        if (k < 1024) w = BT[c] * eh[k];
        else {
            int d = k - 1024;
            w = ((c == d) ? 1.f : 0.f) + AT[c * 512 + d] + BT[c] * em[d];
        }
    }
    _Float16 hi = (_Float16)w;
    g_Whi[s] = hi;
    g_Wlo[s] = (_Float16)((w - (float)hi) * LO_SCALE);

    if (s < NSTATE) {
        float b = (s < 1024) ? (Wx[s] + ex[0] * g_WmB[s]) : (BT[s - 1024] * ex[0]);
        g_wb[s] = b;
    }
    if (s < 2 * BATCH * NSTATE) { g_Shi[s] = (_Float16)0.f; g_Slo[s] = (_Float16)0.f; }
    if (s < 1024) g_bar[s] = 0u;
    if (s < PIPES * 8 * 32 * 64) g_flags[s] = 0u;
}

__launch_bounds__(512, 2)
__global__ void lmu_persist(const float* __restrict__ inputs) {
    __shared__ half8   lwh[SLICE_H8];           // 147456 B: W_hi slice
    __shared__ floatx4 red[PIPES][2][3][64];    // 12288 B: two-phase partials
    __shared__ unsigned lbar[PIPES][4];         // per-pipeline epoch barriers
    __shared__ int s_sl;

    const int tid = threadIdx.x;

    // ---- physical XCD id + rank registration (island = XCD) ----
    unsigned xcd;
    asm volatile("s_getreg_b32 %0, hwreg(HW_REG_XCC_ID)" : "=s"(xcd));
    xcd &= 7u;
    if (tid == 0) {
        unsigned rank = __hip_atomic_fetch_add(g_bar + 512 + xcd * 64, 1u,
                                               __ATOMIC_RELAXED,
                                               __HIP_MEMORY_SCOPE_WORKGROUP);
        s_sl = (int)(rank & 31u);               // column slice [0,32)
    }
    if (tid < PIPES * 4) ((unsigned*)lbar)[tid] = 0u;
    __syncthreads();
    const int isl = (int)xcd;                   // island batch rows isl*16..+16
    const int sl  = s_sl;                       // cols sl*48..+48

    // stage W_hi slice -> LDS (all 8 waves cooperate)
    {
        const half8* src = (const half8*)g_Whi + (size_t)sl * SLICE_H8;
        for (int i = tid; i < SLICE_H8; i += 512) lwh[i] = src[i];
    }

    const int lane = tid & 63, wv = tid >> 6;
    const int p  = wv >> 2;                     // pipeline 0/1
    const int w4 = wv & 3;                      // role within pipeline
    const int quad = lane >> 4, l16 = lane & 15;
    const int kt0 = w4 * 12;                    // this wave's K range
    const int row8 = isl * 16 + p * 8 + l16;    // A-frag row (valid l16<8)

    // pipeline-p flags: this wave consumes producers [8*w4, 8*w4+8)
    unsigned* myprod =
        g_flags + (size_t)(((p * 8 + isl) * 32) + w4 * 8 + (lane & 7)) * 64;
    unsigned* myflag = g_flags + (size_t)(((p * 8 + isl) * 32) + sl) * 64;
    unsigned* bar = (unsigned*)lbar[p];

    // epilogue constants (wave w4<3 handles nt=w4).  Valid C rows are 0-7
    // (= quads 0,1) for BOTH pipelines: A row index = l16, each pipeline
    // loads its 8 batch rows into A rows 0-7.  (r21 bug: picked quads 2,3
    // for p=1 -> stored the zero rows.)
    const int ncol = sl * 48 + w4 * 16 + l16;
    const float wbv = (w4 < 3) ? g_wb[ncol] : 0.f;
    const bool do_tanh = (sl * 48 + w4 * 16) < 1024;
    const bool my_rows = (quad < 2);

    // ---- W_lo: register-resident (36 x half8 = 144 AGPRs), loaded once.
    // Waves wv and wv+4 hold identical copies (same sl, same kt range).
    half8 wr[12 * 3];
    {
        const half8* wlo = (const half8*)g_Wlo + (size_t)sl * SLICE_H8;
#pragma unroll
        for (int ki = 0; ki < 12; ++ki)
#pragma unroll
            for (int nt = 0; nt < 3; ++nt)
                wr[ki * 3 + nt] = wlo[((kt0 + ki) * 3 + nt) * 64 + lane];
    }

    __syncthreads();                            // last WG-wide barrier

    int buf = 0;
    for (int t = 0; t < TSTEPS; ++t) {
        // ---- per-wave dataflow wait on pipeline-p producers ----
        if (t) {
            const unsigned tgt = (unsigned)t;   // flag==t <=> stored step t-1
            bool done = (lane >= 8);
            int spin = 0;
            while (!__all(done)) {
                if (!done) done = (poll_rmw(myprod) >= tgt);
                if (++spin > (1 << 18)) break;  // deadman: no hang
            }
            // CU-local L1 invalidate, then fresh L2-local state loads
            asm volatile("buffer_inv\n\ts_waitcnt vmcnt(0)" ::: "memory");
            __builtin_amdgcn_fence(__ATOMIC_ACQUIRE, "workgroup");
        }

        // PLAIN loads, exec-masked to this pipeline's 8 rows (l16<8);
        // lanes l16>=8 carry zeros -> MFMA C rows 8-15 are zero, ignored.
        const _Float16* shr =
            g_Shi + buf * BATCH * NSTATE + row8 * NSTATE + quad * 8;
        const _Float16* slr =
            g_Slo + buf * BATCH * NSTATE + row8 * NSTATE + quad * 8;

        floatx4 aA[3], aB[3], aC[3];
#pragma unroll
        for (int q = 0; q < 3; ++q) { aA[q] = (floatx4)0.f; aB[q] = (floatx4)0.f; aC[q] = (floatx4)0.f; }

#pragma unroll
        for (int ki = 0; ki < 12; ++ki) {
            const int kt = kt0 + ki;
            half8 ah = (half8)(_Float16)0.f;
            half8 al = (half8)(_Float16)0.f;
            if (l16 < 8) {
                ah = *(const half8*)(shr + kt * 32);
                al = *(const half8*)(slr + kt * 32);
            }
#pragma unroll
            for (int nt = 0; nt < 3; ++nt) {
                half8 bh = lwh[(kt * 3 + nt) * 64 + lane];
                aA[nt] = __builtin_amdgcn_mfma_f32_16x16x32_f16(ah, bh, aA[nt], 0, 0, 0);
                aB[nt] = __builtin_amdgcn_mfma_f32_16x16x32_f16(al, bh, aB[nt], 0, 0, 0);
                aC[nt] = __builtin_amdgcn_mfma_f32_16x16x32_f16(ah, wr[ki * 3 + nt], aC[nt], 0, 0, 0);
            }
        }

        floatx4 P[3];
#pragma unroll
        for (int nt = 0; nt < 3; ++nt)
            P[nt] = aA[nt] + (aB[nt] + aC[nt]) * LO_INV;

        // ---- two-phase K-split reduce, per-pipeline LDS barriers ----
        // red free only after step t-1's epilogue consumed it (3 arrivals/step)
        lds_wait(bar + 2, 3u * (unsigned)t);
        if (w4 < 2) {
#pragma unroll
            for (int nt = 0; nt < 3; ++nt)
                red[p][w4][nt][lane] = P[nt];
            lds_arrive(bar + 0);                // w01 wrote: 2 arrivals/step
        } else {
            lds_wait(bar + 0, 2u * (unsigned)(t + 1));
#pragma unroll
            for (int nt = 0; nt < 3; ++nt)
                red[p][w4 - 2][nt][lane] += P[nt];
            lds_arrive(bar + 1);                // w23 added: 2 arrivals/step
        }

        // waves w4<3: reduce + bias + activation + hi/lo split + PLAIN store
        const int nbuf = buf ^ 1;
        if (w4 < 3) {
            lds_wait(bar + 1, 2u * (unsigned)(t + 1));
            floatx4 vs = red[p][0][w4][lane] + red[p][1][w4][lane];
            if (my_rows) {
                _Float16* dh = g_Shi + nbuf * BATCH * NSTATE;
                _Float16* dl = g_Slo + nbuf * BATCH * NSTATE;
                const float* xt = inputs + t * BATCH + isl * 16 + p * 8 + quad * 4;
#pragma unroll
                for (int r = 0; r < 4; ++r) {
                    int b = isl * 16 + p * 8 + quad * 4 + r;
                    float v = vs[r] + xt[r] * wbv;
                    if (do_tanh) v = fast_tanh(v);
                    _Float16 hi = (_Float16)v;
                    dh[b * NSTATE + ncol] = hi;
                    dl[b * NSTATE + ncol] = (_Float16)((v - (float)hi) * LO_SCALE);
                }
            }
            // drain own stores, then arrive b2; LAST arriver publishes the
            // pipeline's CU flag (one wg-scope RMW +1, island-local L2).
            asm volatile("s_waitcnt vmcnt(0)" ::: "memory");
            __builtin_amdgcn_fence(__ATOMIC_RELEASE, "workgroup");
            if (lane == 0) {
                unsigned old = __hip_atomic_fetch_add(bar + 2, 1u,
                                                      __ATOMIC_ACQ_REL,
                                                      __HIP_MEMORY_SCOPE_WORKGROUP);
                if (old == 3u * (unsigned)t + 2u)
                    __hip_atomic_fetch_add(myflag, 1u, __ATOMIC_RELAXED,
                                           __HIP_MEMORY_SCOPE_WORKGROUP);
            }
        }
        buf = nbuf;
    }
}

// logits + softmax: one WG per batch row (final state in plane 0: 784 even;
// dispatch boundary flushes every XCD's L2 so state is globally visible).
__global__ void lmu_out(const float* __restrict__ Wd, const float* __restrict__ bd,
                        float* __restrict__ out) {
    __shared__ float red[272];
    int b = blockIdx.x;
    const _Float16* sh = g_Shi + b * NSTATE;
    const _Float16* sl = g_Slo + b * NSTATE;
    int tid = threadIdx.x;
    int c = tid & 15, chunk = tid >> 4;
    float part = 0.f;
    if (c < 10) {
        for (int i = chunk * 64; i < chunk * 64 + 64; ++i)
            part += ((float)sh[i] + (float)sl[i] * LO_INV) * Wd[c * 1024 + i];
    }
    red[chunk * 16 + c] = part;
    __syncthreads();
    if (tid < 10) {
        float lg = bd[tid];
        for (int q = 0; q < 16; ++q) lg += red[q * 16 + tid];
        red[256 + tid] = lg;
    }
    __syncthreads();
    if (tid < 10) {
        float mx = red[256];
        for (int q = 1; q < 10; ++q) mx = fmaxf(mx, red[256 + q]);
        float sm = 0.f;
        for (int q = 0; q < 10; ++q) sm += expf(red[256 + q] - mx);
        out[b * 10 + tid] = expf(red[256 + tid] - mx) / sm;
    }
}

extern "C" void kernel_launch(void* const* d_in, const int* in_sizes, int n_in,
                              void* d_out, int out_size, void* d_ws, size_t ws_size,
                              hipStream_t stream) {
    const float* inputs = (const float*)d_in[0];
    const float* e_x    = (const float*)d_in[1];
    const float* e_h    = (const float*)d_in[2];
    const float* e_m    = (const float*)d_in[3];
    const float* W_x    = (const float*)d_in[4];
    const float* W_h    = (const float*)d_in[5];
    const float* W_m    = (const float*)d_in[6];
    const float* AT     = (const float*)d_in[7];
    const float* BT     = (const float*)d_in[8];
    const float* W_d    = (const float*)d_in[9];
    const float* b_d    = (const float*)d_in[10];
    (void)d_ws; (void)ws_size; (void)in_sizes; (void)n_in;

    prep_wmb<<<256, 256, 0, stream>>>(W_m, BT);
    prep_wma<<<dim3(16, 32), 256, 0, stream>>>(W_m, AT);
    prep_wfull<<<9216, 256, 0, stream>>>(W_h, AT, BT, e_h, e_m, e_x, W_x);

    lmu_persist<<<256, 512, 0, stream>>>(inputs);

    lmu_out<<<128, 256, 0, stream>>>(W_d, b_d, (float*)d_out);
}

// Round 5
// 3336.391 us; speedup vs baseline: 2.5318x; 2.5318x over previous
//
#include <hip/hip_runtime.h>
#include <hip/hip_fp16.h>
#include <cmath>

// ---------------------------------------------------------------------------
// LMU fused recurrence.  One 128x1536 @ 1536x1536 GEMM per step (tanh on
// first 1024 cols, linear on last 512), x-dependent rank-1 bias.
// r23 = r18 (flat-barrier base, 3.91 ms) + H-LO ELIMINATION + balanced
// interleaved K assignment.
//   Evidence trail: r19 (2x occupancy) moved NO counter; r20 (per-producer
//   flags) +3%; r22 (dual pipeline) 2.2x WORSE (poll-RMW storm 1.6 GB HBM
//   writes + spin waves starving compute issue).  Scheduling is exhausted;
//   the untouched term is BYTES on the critical path: 96 KB/CU/step L2
//   state fill (3 MB/island broadcast).
//   - h state is now f16 HI-ONLY; m keeps the hi/lo pair.  Rationale: the
//     lo plane exists for the marginally-stable m-recurrence (errors
//     integrate over 784 steps); the h-path is contractive (tanh
//     re-saturates, h->h error gain ~0.6/step, stationary dh ~6e-4; h leaks
//     into m only through the SCALAR u with |e_h|*dh ~ 8e-5/step ->
//     random-walk dm ~2e-3 -> damped by W_m to ~8e-5).  Est. final absmax
//     ~1e-3 vs 9.6e-3 threshold.
//   - Fill: 96 -> 64 KB/CU/step (al loaded only for kt>=32).  MFMA: 108 ->
//     84/wave (aB only on the 4 lo-kts).  Epilogue: lo stored only for
//     m-granules.  lmu_out: h read hi-only.
//   - Wave kt sets INTERLEAVED (wave w owns kt = w+4*ki) so each wave has
//     exactly 4 lo-kts -> balanced waves.  Interleave scatters each wave's
//     producer set over all 32 CUs -> per-producer gating (r20) is
//     pointless; revert to the r13/r18 FLAT island counter (replay-stable,
//     no flag-line storm: 21 MB WRITE_SIZE vs r20's 288 MB / r22's 1.6 GB).
//   Locked-in lessons kept: barrier words touched by atomic RMWs ONLY (r16
//   races; r12 InstCombine demotes fetch_add(0) to a load; r14 sc0 loads
//   served stale from L1).
// Design otherwise = r13/r18:
//   - XCD-local islands (s_getreg XCC_ID + rank registration, 1 WG/CU).
//   - Flat per-island arrival counter in the LOCAL XCD L2 (workgroup-scope
//     RMWs); poll = inline-asm global_atomic_add +0 sc0; busy spin.
//   - W_lo fully register-resident: 36 x half8 = 144 AGPRs/lane.
//   - W_hi slice (147 KB) in LDS; plain L2-local state loads/stores;
//     per-step CU-local L1 buffer_inv.
// Precision: f16 hi/lo weights (lo x2048), m-state hi/lo, h-state hi-only,
// fp32 MFMA accumulate.
// ---------------------------------------------------------------------------

typedef _Float16 half8 __attribute__((ext_vector_type(8)));
typedef float floatx4 __attribute__((ext_vector_type(4)));

#define NSTATE   1536
#define BATCH    128
#define TSTEPS   784
#define KTILES   48
#define ISL_WGS  32                  // WGs per island (= CUs per XCD)
#define SLICE_H8 9216                // half8 per 48-col weight slice (48*3*64)
#define LO_SCALE 2048.0f
#define LO_INV   (1.0f / 2048.0f)

__device__ __align__(16) _Float16 g_Whi[NSTATE * NSTATE];
__device__ __align__(16) _Float16 g_Wlo[NSTATE * NSTATE];
__device__ float    g_wb[NSTATE];
__device__ float    g_WmA[1024 * 512];
__device__ float    g_WmB[1024];
__device__ __align__(16) _Float16 g_Shi[2 * BATCH * NSTATE];
__device__ __align__(16) _Float16 g_Slo[2 * BATCH * NSTATE];
// [xcd*64]: island arrival counters; [512 + xcd*64]: registration counters
__device__ unsigned g_bar[1024];

// Forced local-L2 atomic RMW poll (returns pre-add value).  InstCombine
// cannot demote this to a (stale-L1-cacheable) load -- r12/r14 lessons.
__device__ __forceinline__ unsigned poll_rmw(unsigned* p) {
    unsigned old;
    asm volatile("global_atomic_add %0, %1, %2, off sc0\n\ts_waitcnt vmcnt(0)"
                 : "=&v"(old)
                 : "v"(p), "v"(0u)
                 : "memory");
    return old;
}

// Branch-free tanh: 1 - 2/(e^{2x}+1).  __expf -> v_exp_f32.  Exact limits:
// e=inf -> 1, e=0 -> -1.  |err| ~1e-7.
__device__ __forceinline__ float fast_tanh(float x) {
    float e = __expf(2.f * x);
    return 1.f - 2.f / (e + 1.f);
}

// W_mB[i] = sum_c W_m[i,c] * BT[c]
__global__ void prep_wmb(const float* __restrict__ Wm, const float* __restrict__ BT) {
    int row  = blockIdx.x * 4 + (threadIdx.x >> 6);
    int lane = threadIdx.x & 63;
    float s = 0.f;
    for (int c = lane; c < 512; c += 64) s += Wm[row * 512 + c] * BT[c];
    for (int o = 32; o; o >>= 1) s += __shfl_down(s, o);
    if (lane == 0) g_WmB[row] = s;
}

// W_mA = W_m @ (I + AT)
__global__ void prep_wma(const float* __restrict__ Wm, const float* __restrict__ AT) {
    __shared__ float As[32][33], Bs[32][33];
    int d0 = blockIdx.x * 32, i0 = blockIdx.y * 32;
    int tx = threadIdx.x & 31, ty = threadIdx.x >> 5;
    float acc[4];
#pragma unroll
    for (int r = 0; r < 4; ++r) acc[r] = Wm[(i0 + ty + 8 * r) * 512 + d0 + tx];
    for (int c0 = 0; c0 < 512; c0 += 32) {
#pragma unroll
        for (int r = 0; r < 4; ++r) {
            As[ty + 8 * r][tx] = Wm[(i0 + ty + 8 * r) * 512 + c0 + tx];
            Bs[ty + 8 * r][tx] = AT[(c0 + ty + 8 * r) * 512 + d0 + tx];
        }
        __syncthreads();
#pragma unroll
        for (int c = 0; c < 32; ++c)
#pragma unroll
            for (int r = 0; r < 4; ++r) acc[r] += As[ty + 8 * r][c] * Bs[c][tx];
        __syncthreads();
    }
#pragma unroll
    for (int r = 0; r < 4; ++r) g_WmA[(i0 + ty + 8 * r) * 512 + d0 + tx] = acc[r];
}

// Build W_full, f16 hi/lo (lo x2048), in slice-major fragment order:
// storage s = (((sl*48 + kt)*3 + nt)*64 + lane)*8 + j
//   n = sl*48 + nt*16 + (lane&15),  k = kt*32 + ((lane>>4)&3)*8 + j
__global__ void prep_wfull(const float* __restrict__ Wh, const float* __restrict__ AT,
                           const float* __restrict__ BT, const float* __restrict__ eh,
                           const float* __restrict__ em, const float* __restrict__ ex,
                           const float* __restrict__ Wx) {
    int s = blockIdx.x * 256 + threadIdx.x;     // [0, 1536*1536)
    int j8 = s & 7;
    int u = s >> 3;
    int lane = u & 63;
    u >>= 6;                                    // [0, 4608)
    int nt = u % 3; u /= 3;
    int kt = u % 48;
    int sl = u / 48;
    int n = sl * 48 + nt * 16 + (lane & 15);
    int k = kt * 32 + ((lane >> 4) & 3) * 8 + j8;

    float w;
    if (n < 1024) {
        if (k < 1024) w = Wh[n * 1024 + k] + g_WmB[n] * eh[k];
        else          w = g_WmA[n * 512 + (k - 1024)] + g_WmB[n] * em[k - 1024];
    } else {
        int c = n - 1024;
        if (k < 1024) w = BT[c] * eh[k];
        else {
            int d = k - 1024;
            w = ((c == d) ? 1.f : 0.f) + AT[c * 512 + d] + BT[c] * em[d];
        }
    }
    _Float16 hi = (_Float16)w;
    g_Whi[s] = hi;
    g_Wlo[s] = (_Float16)((w - (float)hi) * LO_SCALE);

    if (s < NSTATE) {
        float b = (s < 1024) ? (Wx[s] + ex[0] * g_WmB[s]) : (BT[s - 1024] * ex[0]);
        g_wb[s] = b;
    }
    if (s < 2 * BATCH * NSTATE) { g_Shi[s] = (_Float16)0.f; g_Slo[s] = (_Float16)0.f; }
    if (s < 1024) g_bar[s] = 0u;
}

__launch_bounds__(256, 1)
__global__ void lmu_persist(const float* __restrict__ inputs) {
    __shared__ half8  lwh[SLICE_H8];            // 147456 B: W_hi slice
    __shared__ float4 red[4 * 3 * 64];          // 12288 B: K-split partials
    __shared__ int    s_sl;

    const int tid = threadIdx.x;

    // ---- physical XCD id + rank registration (island = XCD) ----
    unsigned xcd;
    asm volatile("s_getreg_b32 %0, hwreg(HW_REG_XCC_ID)" : "=s"(xcd));
    xcd &= 7u;
    if (tid == 0) {
        unsigned rank = __hip_atomic_fetch_add(g_bar + 512 + xcd * 64, 1u,
                                               __ATOMIC_RELAXED,
                                               __HIP_MEMORY_SCOPE_WORKGROUP);
        s_sl = (int)(rank & 31u);               // column slice [0,32)
    }
    __syncthreads();
    const int isl = (int)xcd;                   // batch rows isl*16..+16
    const int sl  = s_sl;                       // cols sl*48..+48

    // stage W_hi slice -> LDS
    {
        const half8* src = (const half8*)g_Whi + (size_t)sl * SLICE_H8;
        for (int i = tid; i < SLICE_H8; i += 256) lwh[i] = src[i];
    }

    const int lane = tid & 63, wv = tid >> 6;
    const int quad = lane >> 4, l16 = lane & 15;
    const int rowA = isl * 16 + l16;            // A-frag batch row
    unsigned* cnt = g_bar + isl * 64;           // island arrival counter (local L2)

    // INTERLEAVED kt set: wave wv owns kt = wv + 4*ki, ki in [0,12).
    // ki>=8 <=> kt>=32 <=> m-columns (lo plane live) -- 4 per wave, balanced.

    // epilogue constants (wave wv<3 handles nt=wv)
    const int ncol = sl * 48 + wv * 16 + l16;
    const float wbv = (wv < 3) ? g_wb[ncol] : 0.f;
    const bool do_tanh = (sl * 48 + wv * 16) < 1024;   // h-granule: no lo store

    // ---- W_lo: FULLY register-resident (36 x half8 = 144 AGPRs), loaded once
    half8 wr[12 * 3];
    {
        const half8* wlo = (const half8*)g_Wlo + (size_t)sl * SLICE_H8;
#pragma unroll
        for (int ki = 0; ki < 12; ++ki)
#pragma unroll
            for (int nt = 0; nt < 3; ++nt)
                wr[ki * 3 + nt] = wlo[((wv + 4 * ki) * 3 + nt) * 64 + lane];
    }

    __syncthreads();

    int buf = 0;
    for (int t = 0; t < TSTEPS; ++t) {
        // PLAIN loads: producers share this XCD's L2 -> L2-local traffic
        const _Float16* shr =
            g_Shi + buf * BATCH * NSTATE + rowA * NSTATE + quad * 8;
        const _Float16* slr =
            g_Slo + buf * BATCH * NSTATE + rowA * NSTATE + quad * 8;

        floatx4 aA[3], aB[3], aC[3];
#pragma unroll
        for (int q = 0; q < 3; ++q) { aA[q] = (floatx4)0.f; aB[q] = (floatx4)0.f; aC[q] = (floatx4)0.f; }

#pragma unroll
        for (int ki = 0; ki < 12; ++ki) {
            const int kt = wv + 4 * ki;
            half8 ah = *(const half8*)(shr + kt * 32);
            half8 al = (half8)(_Float16)0.f;
            if (ki >= 8)                         // m-cols only: lo plane live
                al = *(const half8*)(slr + kt * 32);
#pragma unroll
            for (int nt = 0; nt < 3; ++nt) {
                half8 bh = lwh[(kt * 3 + nt) * 64 + lane];
                aA[nt] = __builtin_amdgcn_mfma_f32_16x16x32_f16(ah, bh, aA[nt], 0, 0, 0);
                if (ki >= 8)
                    aB[nt] = __builtin_amdgcn_mfma_f32_16x16x32_f16(al, bh, aB[nt], 0, 0, 0);
                aC[nt] = __builtin_amdgcn_mfma_f32_16x16x32_f16(ah, wr[ki * 3 + nt], aC[nt], 0, 0, 0);
            }
        }

        // K-split partials -> LDS
#pragma unroll
        for (int nt = 0; nt < 3; ++nt) {
            floatx4 P = aA[nt] + (aB[nt] + aC[nt]) * LO_INV;
            red[(wv * 3 + nt) * 64 + lane] = float4{P[0], P[1], P[2], P[3]};
        }
        __syncthreads();

        // waves 0-2: reduce + bias + activation + hi/lo split + PLAIN store
        const int nbuf = buf ^ 1;
        if (wv < 3) {
            float4 v0 = red[(0 * 3 + wv) * 64 + lane];
            float4 v1 = red[(1 * 3 + wv) * 64 + lane];
            float4 v2 = red[(2 * 3 + wv) * 64 + lane];
            float4 v3 = red[(3 * 3 + wv) * 64 + lane];
            float vr4[4] = {v0.x + v1.x + v2.x + v3.x, v0.y + v1.y + v2.y + v3.y,
                            v0.z + v1.z + v2.z + v3.z, v0.w + v1.w + v2.w + v3.w};
            _Float16* dh = g_Shi + nbuf * BATCH * NSTATE;
            _Float16* dl = g_Slo + nbuf * BATCH * NSTATE;
            const float* xt = inputs + t * BATCH + isl * 16 + quad * 4;
            if (do_tanh) {
                // h-granule: f16 hi only, no lo store
#pragma unroll
                for (int r = 0; r < 4; ++r) {
                    int b = isl * 16 + quad * 4 + r;
                    float v = fast_tanh(vr4[r] + xt[r] * wbv);
                    dh[b * NSTATE + ncol] = (_Float16)v;
                }
            } else {
                // m-granule: keep hi/lo pair
#pragma unroll
                for (int r = 0; r < 4; ++r) {
                    int b = isl * 16 + quad * 4 + r;
                    float v = vr4[r] + xt[r] * wbv;
                    _Float16 hi = (_Float16)v;
                    dh[b * NSTATE + ncol] = hi;
                    dl[b * NSTATE + ncol] = (_Float16)((v - (float)hi) * LO_SCALE);
                }
            }
        }

        // drain stores (syncthreads emits vmcnt(0)), then flat LOCAL-L2
        // barrier: arrival = wg-scope RMW(+1); poll = asm RMW(+0) sc0.
        __builtin_amdgcn_fence(__ATOMIC_RELEASE, "workgroup");
        __syncthreads();
        if (tid == 0) {
            __hip_atomic_fetch_add(cnt, 1u, __ATOMIC_RELAXED,
                                   __HIP_MEMORY_SCOPE_WORKGROUP);
            const unsigned target = (unsigned)ISL_WGS * (unsigned)(t + 1);
            int spin = 0;
            while (poll_rmw(cnt) < target) {
                if (++spin > (1 << 18)) break;  // deadman: no hang
            }
        }
        __syncthreads();
        // CU-local L1 invalidate only (L2 holds the island's fresh state)
        asm volatile("buffer_inv\n\ts_waitcnt vmcnt(0)" ::: "memory");
        __builtin_amdgcn_fence(__ATOMIC_ACQUIRE, "workgroup");
        buf = nbuf;
    }
}

// logits + softmax: one WG per batch row (final state in plane 0: 784 even;
// dispatch boundary flushes every XCD's L2 so state is globally visible).
// h is f16 HI-ONLY now (cols < 1024 feed the dense layer).
__global__ void lmu_out(const float* __restrict__ Wd, const float* __restrict__ bd,
                        float* __restrict__ out) {
    __shared__ float red[272];
    int b = blockIdx.x;
    const _Float16* sh = g_Shi + b * NSTATE;
    int tid = threadIdx.x;
    int c = tid & 15, chunk = tid >> 4;
    float part = 0.f;
    if (c < 10) {
        for (int i = chunk * 64; i < chunk * 64 + 64; ++i)
            part += (float)sh[i] * Wd[c * 1024 + i];
    }
    red[chunk * 16 + c] = part;
    __syncthreads();
    if (tid < 10) {
        float lg = bd[tid];
        for (int q = 0; q < 16; ++q) lg += red[q * 16 + tid];
        red[256 + tid] = lg;
    }
    __syncthreads();
    if (tid < 10) {
        float mx = red[256];
        for (int q = 1; q < 10; ++q) mx = fmaxf(mx, red[256 + q]);
        float sm = 0.f;
        for (int q = 0; q < 10; ++q) sm += expf(red[256 + q] - mx);
        out[b * 10 + tid] = expf(red[256 + tid] - mx) / sm;
    }
}

extern "C" void kernel_launch(void* const* d_in, const int* in_sizes, int n_in,
                              void* d_out, int out_size, void* d_ws, size_t ws_size,
                              hipStream_t stream) {
    const float* inputs = (const float*)d_in[0];
    const float* e_x    = (const float*)d_in[1];
    const float* e_h    = (const float*)d_in[2];
    const float* e_m    = (const float*)d_in[3];
    const float* W_x    = (const float*)d_in[4];
    const float* W_h    = (const float*)d_in[5];
    const float* W_m    = (const float*)d_in[6];
    const float* AT     = (const float*)d_in[7];
    const float* BT     = (const float*)d_in[8];
    const float* W_d    = (const float*)d_in[9];
    const float* b_d    = (const float*)d_in[10];
    (void)d_ws; (void)ws_size; (void)in_sizes; (void)n_in;

    prep_wmb<<<256, 256, 0, stream>>>(W_m, BT);
    prep_wma<<<dim3(16, 32), 256, 0, stream>>>(W_m, AT);
    prep_wfull<<<9216, 256, 0, stream>>>(W_h, AT, BT, e_h, e_m, e_x, W_x);

    lmu_persist<<<256, 256, 0, stream>>>(inputs);

    lmu_out<<<128, 256, 0, stream>>>(W_d, b_d, (float*)d_out);
}

// Round 6
// 3330.999 us; speedup vs baseline: 2.5359x; 1.0016x over previous
//
#include <hip/hip_runtime.h>
#include <hip/hip_fp16.h>
#include <cmath>

// ---------------------------------------------------------------------------
// LMU fused recurrence.  One 128x1536 @ 1536x1536 GEMM per step (tanh on
// first 1024 cols, linear on last 512), x-dependent rank-1 bias.
// r24 = r23 (3.34 ms: h-lo elimination + interleaved kt) + POLL BACKOFF.
//   Theory: the flat island barrier's tail is ~1.5-2 us/step.  32 CUs
//   back-to-back RMW-poll ONE L2 line; same-address atomics serialize at
//   the TCC, so the last arrival's +1 queues behind ~32 in-flight poll
//   RMWs, and every poller then needs one MORE serviced RMW to observe it
//   (~2 serialized rounds ~ 1200-1900 cy at DVFS clock).  s_sleep(4)
//   (~256 cy) between failed polls cuts line pressure ~15x: arrival lands
//   in a near-empty queue, discovery <= sleep + 1 RMW round-trip.
//   Signature prediction: WRITE_SIZE 19.9 -> <12 MB (poll RMWs write
//   through to HBM -- r20/r22 evidence), dur 3336 -> 2900-3150 us.
//   Prior session A/B'd arrival-path variants (r15 tree, r17 sweep) but
//   never de-intensified the POLL side.
// Evidence trail: r19 (2x occupancy) no counter moved; r20 (per-producer
//   flags) +3%; r22 (dual pipeline) 2.2x worse (RMW storm); r23 (h-lo cut,
//   -33% fill bytes) -12% == fill bytes ARE on the critical path, fill is
//   L1-interface service-bound (r19 null), only byte cuts or sync-tail
//   cuts remain.
//   Locked-in lessons: barrier words touched by atomic RMWs ONLY (r16
//   races; r12 InstCombine demotes fetch_add(0) to a load; r14 sc0 loads
//   served stale from L1).
// Design = r23:
//   - h state f16 HI-ONLY; m keeps hi/lo (lo x2048).  Interleaved kt sets
//     (wave w owns kt = w+4*ki; ki>=8 <=> m-cols, 4 lo-kts per wave).
//   - XCD-local islands (s_getreg XCC_ID + rank registration, 1 WG/CU).
//   - Flat per-island arrival counter in the LOCAL XCD L2 (workgroup-scope
//     RMWs); poll = inline-asm global_atomic_add +0 sc0; sleep-backoff spin.
//   - W_lo fully register-resident: 36 x half8 = 144 AGPRs/lane.
//   - W_hi slice (147 KB) in LDS; plain L2-local state loads/stores;
//     per-step CU-local L1 buffer_inv.
// Precision: f16 hi/lo weights (lo x2048), m-state hi/lo, h-state hi-only,
// fp32 MFMA accumulate.  Verified absmax 9.8e-4 (threshold 9.6e-3).
// ---------------------------------------------------------------------------

typedef _Float16 half8 __attribute__((ext_vector_type(8)));
typedef float floatx4 __attribute__((ext_vector_type(4)));

#define NSTATE   1536
#define BATCH    128
#define TSTEPS   784
#define KTILES   48
#define ISL_WGS  32                  // WGs per island (= CUs per XCD)
#define SLICE_H8 9216                // half8 per 48-col weight slice (48*3*64)
#define LO_SCALE 2048.0f
#define LO_INV   (1.0f / 2048.0f)

__device__ __align__(16) _Float16 g_Whi[NSTATE * NSTATE];
__device__ __align__(16) _Float16 g_Wlo[NSTATE * NSTATE];
__device__ float    g_wb[NSTATE];
__device__ float    g_WmA[1024 * 512];
__device__ float    g_WmB[1024];
__device__ __align__(16) _Float16 g_Shi[2 * BATCH * NSTATE];
__device__ __align__(16) _Float16 g_Slo[2 * BATCH * NSTATE];
// [xcd*64]: island arrival counters; [512 + xcd*64]: registration counters
__device__ unsigned g_bar[1024];

// Forced local-L2 atomic RMW poll (returns pre-add value).  InstCombine
// cannot demote this to a (stale-L1-cacheable) load -- r12/r14 lessons.
__device__ __forceinline__ unsigned poll_rmw(unsigned* p) {
    unsigned old;
    asm volatile("global_atomic_add %0, %1, %2, off sc0\n\ts_waitcnt vmcnt(0)"
                 : "=&v"(old)
                 : "v"(p), "v"(0u)
                 : "memory");
    return old;
}

// Branch-free tanh: 1 - 2/(e^{2x}+1).  __expf -> v_exp_f32.  Exact limits:
// e=inf -> 1, e=0 -> -1.  |err| ~1e-7.
__device__ __forceinline__ float fast_tanh(float x) {
    float e = __expf(2.f * x);
    return 1.f - 2.f / (e + 1.f);
}

// W_mB[i] = sum_c W_m[i,c] * BT[c]
__global__ void prep_wmb(const float* __restrict__ Wm, const float* __restrict__ BT) {
    int row  = blockIdx.x * 4 + (threadIdx.x >> 6);
    int lane = threadIdx.x & 63;
    float s = 0.f;
    for (int c = lane; c < 512; c += 64) s += Wm[row * 512 + c] * BT[c];
    for (int o = 32; o; o >>= 1) s += __shfl_down(s, o);
    if (lane == 0) g_WmB[row] = s;
}

// W_mA = W_m @ (I + AT)
__global__ void prep_wma(const float* __restrict__ Wm, const float* __restrict__ AT) {
    __shared__ float As[32][33], Bs[32][33];
    int d0 = blockIdx.x * 32, i0 = blockIdx.y * 32;
    int tx = threadIdx.x & 31, ty = threadIdx.x >> 5;
    float acc[4];
#pragma unroll
    for (int r = 0; r < 4; ++r) acc[r] = Wm[(i0 + ty + 8 * r) * 512 + d0 + tx];
    for (int c0 = 0; c0 < 512; c0 += 32) {
#pragma unroll
        for (int r = 0; r < 4; ++r) {
            As[ty + 8 * r][tx] = Wm[(i0 + ty + 8 * r) * 512 + c0 + tx];
            Bs[ty + 8 * r][tx] = AT[(c0 + ty + 8 * r) * 512 + d0 + tx];
        }
        __syncthreads();
#pragma unroll
        for (int c = 0; c < 32; ++c)
#pragma unroll
            for (int r = 0; r < 4; ++r) acc[r] += As[ty + 8 * r][c] * Bs[c][tx];
        __syncthreads();
    }
#pragma unroll
    for (int r = 0; r < 4; ++r) g_WmA[(i0 + ty + 8 * r) * 512 + d0 + tx] = acc[r];
}

// Build W_full, f16 hi/lo (lo x2048), in slice-major fragment order:
// storage s = (((sl*48 + kt)*3 + nt)*64 + lane)*8 + j
//   n = sl*48 + nt*16 + (lane&15),  k = kt*32 + ((lane>>4)&3)*8 + j
__global__ void prep_wfull(const float* __restrict__ Wh, const float* __restrict__ AT,
                           const float* __restrict__ BT, const float* __restrict__ eh,
                           const float* __restrict__ em, const float* __restrict__ ex,
                           const float* __restrict__ Wx) {
    int s = blockIdx.x * 256 + threadIdx.x;     // [0, 1536*1536)
    int j8 = s & 7;
    int u = s >> 3;
    int lane = u & 63;
    u >>= 6;                                    // [0, 4608)
    int nt = u % 3; u /= 3;
    int kt = u % 48;
    int sl = u / 48;
    int n = sl * 48 + nt * 16 + (lane & 15);
    int k = kt * 32 + ((lane >> 4) & 3) * 8 + j8;

    float w;
    if (n < 1024) {
        if (k < 1024) w = Wh[n * 1024 + k] + g_WmB[n] * eh[k];
        else          w = g_WmA[n * 512 + (k - 1024)] + g_WmB[n] * em[k - 1024];
    } else {
        int c = n - 1024;
        if (k < 1024) w = BT[c] * eh[k];
        else {
            int d = k - 1024;
            w = ((c == d) ? 1.f : 0.f) + AT[c * 512 + d] + BT[c] * em[d];
        }
    }
    _Float16 hi = (_Float16)w;
    g_Whi[s] = hi;
    g_Wlo[s] = (_Float16)((w - (float)hi) * LO_SCALE);

    if (s < NSTATE) {
        float b = (s < 1024) ? (Wx[s] + ex[0] * g_WmB[s]) : (BT[s - 1024] * ex[0]);
        g_wb[s] = b;
    }
    if (s < 2 * BATCH * NSTATE) { g_Shi[s] = (_Float16)0.f; g_Slo[s] = (_Float16)0.f; }
    if (s < 1024) g_bar[s] = 0u;
}

__launch_bounds__(256, 1)
__global__ void lmu_persist(const float* __restrict__ inputs) {
    __shared__ half8  lwh[SLICE_H8];            // 147456 B: W_hi slice
    __shared__ float4 red[4 * 3 * 64];          // 12288 B: K-split partials
    __shared__ int    s_sl;

    const int tid = threadIdx.x;

    // ---- physical XCD id + rank registration (island = XCD) ----
    unsigned xcd;
    asm volatile("s_getreg_b32 %0, hwreg(HW_REG_XCC_ID)" : "=s"(xcd));
    xcd &= 7u;
    if (tid == 0) {
        unsigned rank = __hip_atomic_fetch_add(g_bar + 512 + xcd * 64, 1u,
                                               __ATOMIC_RELAXED,
                                               __HIP_MEMORY_SCOPE_WORKGROUP);
        s_sl = (int)(rank & 31u);               // column slice [0,32)
    }
    __syncthreads();
    const int isl = (int)xcd;                   // batch rows isl*16..+16
    const int sl  = s_sl;                       // cols sl*48..+48

    // stage W_hi slice -> LDS
    {
        const half8* src = (const half8*)g_Whi + (size_t)sl * SLICE_H8;
        for (int i = tid; i < SLICE_H8; i += 256) lwh[i] = src[i];
    }

    const int lane = tid & 63, wv = tid >> 6;
    const int quad = lane >> 4, l16 = lane & 15;
    const int rowA = isl * 16 + l16;            // A-frag batch row
    unsigned* cnt = g_bar + isl * 64;           // island arrival counter (local L2)

    // INTERLEAVED kt set: wave wv owns kt = wv + 4*ki, ki in [0,12).
    // ki>=8 <=> kt>=32 <=> m-columns (lo plane live) -- 4 per wave, balanced.

    // epilogue constants (wave wv<3 handles nt=wv)
    const int ncol = sl * 48 + wv * 16 + l16;
    const float wbv = (wv < 3) ? g_wb[ncol] : 0.f;
    const bool do_tanh = (sl * 48 + wv * 16) < 1024;   // h-granule: no lo store

    // ---- W_lo: FULLY register-resident (36 x half8 = 144 AGPRs), loaded once
    half8 wr[12 * 3];
    {
        const half8* wlo = (const half8*)g_Wlo + (size_t)sl * SLICE_H8;
#pragma unroll
        for (int ki = 0; ki < 12; ++ki)
#pragma unroll
            for (int nt = 0; nt < 3; ++nt)
                wr[ki * 3 + nt] = wlo[((wv + 4 * ki) * 3 + nt) * 64 + lane];
    }

    __syncthreads();

    int buf = 0;
    for (int t = 0; t < TSTEPS; ++t) {
        // PLAIN loads: producers share this XCD's L2 -> L2-local traffic
        const _Float16* shr =
            g_Shi + buf * BATCH * NSTATE + rowA * NSTATE + quad * 8;
        const _Float16* slr =
            g_Slo + buf * BATCH * NSTATE + rowA * NSTATE + quad * 8;

        floatx4 aA[3], aB[3], aC[3];
#pragma unroll
        for (int q = 0; q < 3; ++q) { aA[q] = (floatx4)0.f; aB[q] = (floatx4)0.f; aC[q] = (floatx4)0.f; }

#pragma unroll
        for (int ki = 0; ki < 12; ++ki) {
            const int kt = wv + 4 * ki;
            half8 ah = *(const half8*)(shr + kt * 32);
            half8 al = (half8)(_Float16)0.f;
            if (ki >= 8)                         // m-cols only: lo plane live
                al = *(const half8*)(slr + kt * 32);
#pragma unroll
            for (int nt = 0; nt < 3; ++nt) {
                half8 bh = lwh[(kt * 3 + nt) * 64 + lane];
                aA[nt] = __builtin_amdgcn_mfma_f32_16x16x32_f16(ah, bh, aA[nt], 0, 0, 0);
                if (ki >= 8)
                    aB[nt] = __builtin_amdgcn_mfma_f32_16x16x32_f16(al, bh, aB[nt], 0, 0, 0);
                aC[nt] = __builtin_amdgcn_mfma_f32_16x16x32_f16(ah, wr[ki * 3 + nt], aC[nt], 0, 0, 0);
            }
        }

        // K-split partials -> LDS
#pragma unroll
        for (int nt = 0; nt < 3; ++nt) {
            floatx4 P = aA[nt] + (aB[nt] + aC[nt]) * LO_INV;
            red[(wv * 3 + nt) * 64 + lane] = float4{P[0], P[1], P[2], P[3]};
        }
        __syncthreads();

        // waves 0-2: reduce + bias + activation + hi/lo split + PLAIN store
        const int nbuf = buf ^ 1;
        if (wv < 3) {
            float4 v0 = red[(0 * 3 + wv) * 64 + lane];
            float4 v1 = red[(1 * 3 + wv) * 64 + lane];
            float4 v2 = red[(2 * 3 + wv) * 64 + lane];
            float4 v3 = red[(3 * 3 + wv) * 64 + lane];
            float vr4[4] = {v0.x + v1.x + v2.x + v3.x, v0.y + v1.y + v2.y + v3.y,
                            v0.z + v1.z + v2.z + v3.z, v0.w + v1.w + v2.w + v3.w};
            _Float16* dh = g_Shi + nbuf * BATCH * NSTATE;
            _Float16* dl = g_Slo + nbuf * BATCH * NSTATE;
            const float* xt = inputs + t * BATCH + isl * 16 + quad * 4;
            if (do_tanh) {
                // h-granule: f16 hi only, no lo store
#pragma unroll
                for (int r = 0; r < 4; ++r) {
                    int b = isl * 16 + quad * 4 + r;
                    float v = fast_tanh(vr4[r] + xt[r] * wbv);
                    dh[b * NSTATE + ncol] = (_Float16)v;
                }
            } else {
                // m-granule: keep hi/lo pair
#pragma unroll
                for (int r = 0; r < 4; ++r) {
                    int b = isl * 16 + quad * 4 + r;
                    float v = vr4[r] + xt[r] * wbv;
                    _Float16 hi = (_Float16)v;
                    dh[b * NSTATE + ncol] = hi;
                    dl[b * NSTATE + ncol] = (_Float16)((v - (float)hi) * LO_SCALE);
                }
            }
        }

        // drain stores (syncthreads emits vmcnt(0)), then flat LOCAL-L2
        // barrier: arrival = wg-scope RMW(+1); poll = asm RMW(+0) sc0 with
        // s_sleep(4) (~256 cy) backoff between failed polls -- keeps the
        // counter line's TCC queue near-empty so the LAST arrival and the
        // subsequent observing polls are serviced immediately (the r24
        // lever; back-to-back polling serialized ~2 rounds of 32 RMWs).
        __builtin_amdgcn_fence(__ATOMIC_RELEASE, "workgroup");
        __syncthreads();
        if (tid == 0) {
            __hip_atomic_fetch_add(cnt, 1u, __ATOMIC_RELAXED,
                                   __HIP_MEMORY_SCOPE_WORKGROUP);
            const unsigned target = (unsigned)ISL_WGS * (unsigned)(t + 1);
            int spin = 0;
            while (poll_rmw(cnt) < target) {
                __builtin_amdgcn_s_sleep(4);    // ~256 cy low-power backoff
                if (++spin > (1 << 18)) break;  // deadman: no hang
            }
        }
        __syncthreads();
        // CU-local L1 invalidate only (L2 holds the island's fresh state)
        asm volatile("buffer_inv\n\ts_waitcnt vmcnt(0)" ::: "memory");
        __builtin_amdgcn_fence(__ATOMIC_ACQUIRE, "workgroup");
        buf = nbuf;
    }
}

// logits + softmax: one WG per batch row (final state in plane 0: 784 even;
// dispatch boundary flushes every XCD's L2 so state is globally visible).
// h is f16 HI-ONLY (cols < 1024 feed the dense layer).
__global__ void lmu_out(const float* __restrict__ Wd, const float* __restrict__ bd,
                        float* __restrict__ out) {
    __shared__ float red[272];
    int b = blockIdx.x;
    const _Float16* sh = g_Shi + b * NSTATE;
    int tid = threadIdx.x;
    int c = tid & 15, chunk = tid >> 4;
    float part = 0.f;
    if (c < 10) {
        for (int i = chunk * 64; i < chunk * 64 + 64; ++i)
            part += (float)sh[i] * Wd[c * 1024 + i];
    }
    red[chunk * 16 + c] = part;
    __syncthreads();
    if (tid < 10) {
        float lg = bd[tid];
        for (int q = 0; q < 16; ++q) lg += red[q * 16 + tid];
        red[256 + tid] = lg;
    }
    __syncthreads();
    if (tid < 10) {
        float mx = red[256];
        for (int q = 1; q < 10; ++q) mx = fmaxf(mx, red[256 + q]);
        float sm = 0.f;
        for (int q = 0; q < 10; ++q) sm += expf(red[256 + q] - mx);
        out[b * 10 + tid] = expf(red[256 + tid] - mx) / sm;
    }
}

extern "C" void kernel_launch(void* const* d_in, const int* in_sizes, int n_in,
                              void* d_out, int out_size, void* d_ws, size_t ws_size,
                              hipStream_t stream) {
    const float* inputs = (const float*)d_in[0];
    const float* e_x    = (const float*)d_in[1];
    const float* e_h    = (const float*)d_in[2];
    const float* e_m    = (const float*)d_in[3];
    const float* W_x    = (const float*)d_in[4];
    const float* W_h    = (const float*)d_in[5];
    const float* W_m    = (const float*)d_in[6];
    const float* AT     = (const float*)d_in[7];
    const float* BT     = (const float*)d_in[8];
    const float* W_d    = (const float*)d_in[9];
    const float* b_d    = (const float*)d_in[10];
    (void)d_ws; (void)ws_size; (void)in_sizes; (void)n_in;

    prep_wmb<<<256, 256, 0, stream>>>(W_m, BT);
    prep_wma<<<dim3(16, 32), 256, 0, stream>>>(W_m, AT);
    prep_wfull<<<9216, 256, 0, stream>>>(W_h, AT, BT, e_h, e_m, e_x, W_x);

    lmu_persist<<<256, 256, 0, stream>>>(inputs);

    lmu_out<<<128, 256, 0, stream>>>(W_d, b_d, (float*)d_out);
}

// Round 7
// 3317.905 us; speedup vs baseline: 2.5459x; 1.0039x over previous
//
#include <hip/hip_runtime.h>
#include <hip/hip_fp16.h>
#include <cmath>

// ---------------------------------------------------------------------------
// LMU fused recurrence.  One 128x1536 @ 1536x1536 GEMM per step (tanh on
// first 1024 cols, linear on last 512), x-dependent rank-1 bias.
// r25 = r24 (3.33 ms) + EXPLICIT TWO-PHASE STATE FILL.
//   Theory: the per-step 64 KB/CU state fill is LATENCY-SERIALIZED, not
//   pipelined.  All state lines miss L1 (post-buffer_inv); the compiler's
//   register-pressure heuristics keep each 16B load near its consuming
//   MFMA, so every load pays a full ~250cy L2 round-trip serially:
//   12-24 x 250cy ~ 1.2-2.5 us of the 4.25 us step.  This ALSO re-explains
//   r19's null: at 2 waves/SIMD VGPR dropped 144->92 -- even less hoist
//   room, each wave's fill MORE serialized, cancelling the occupancy gain.
//   Fix: stage all 16 loads (12 ah + 4 al) into named registers, pin with
//   sched_barrier(0), then the 84-MFMA phase.  First MFMA waits only on
//   the oldest load (vmcnt counting) -> fill ~ 1 latency + 16 service.
//   Cost: ~64 extra VGPR; fine at 1 wave/SIMD (512-reg unified budget).
//   Prediction: VGPR ~200; dur -> 2700-2950 us if right; neutral+VGPR-up
//   falsifies latency-serialization => fill is service-bound => structural
//   floor reached.
// Evidence trail: r19 (2x occupancy) null; r20 (per-producer flags) +3%;
//   r22 (dual pipeline) 2.2x worse (RMW storm); r23 (h-lo cut, -33% fill
//   bytes) -12% => fill bytes ARE on the critical path; r24 (poll backoff)
//   null => poll contention is NOT the tail.
//   Locked-in lessons: barrier words touched by atomic RMWs ONLY (r16
//   races; r12 InstCombine demotes fetch_add(0) to a load; r14 sc0 loads
//   served stale from L1).
// Design = r23/r24:
//   - h state f16 HI-ONLY; m keeps hi/lo (lo x2048).  Interleaved kt sets
//     (wave w owns kt = w+4*ki; ki>=8 <=> m-cols, 4 lo-kts per wave).
//   - XCD-local islands (s_getreg XCC_ID + rank registration, 1 WG/CU).
//   - Flat per-island arrival counter in the LOCAL XCD L2 (workgroup-scope
//     RMWs); poll = inline-asm global_atomic_add +0 sc0; sleep-backoff spin.
//   - W_lo fully register-resident: 36 x half8 = 144 AGPRs/lane.
//   - W_hi slice (147 KB) in LDS; plain L2-local state loads/stores;
//     per-step CU-local L1 buffer_inv.
// Precision: f16 hi/lo weights (lo x2048), m-state hi/lo, h-state hi-only,
// fp32 MFMA accumulate.  Verified absmax 9.8e-4 (threshold 9.6e-3).
// ---------------------------------------------------------------------------

typedef _Float16 half8 __attribute__((ext_vector_type(8)));
typedef float floatx4 __attribute__((ext_vector_type(4)));

#define NSTATE   1536
#define BATCH    128
#define TSTEPS   784
#define KTILES   48
#define ISL_WGS  32                  // WGs per island (= CUs per XCD)
#define SLICE_H8 9216                // half8 per 48-col weight slice (48*3*64)
#define LO_SCALE 2048.0f
#define LO_INV   (1.0f / 2048.0f)

__device__ __align__(16) _Float16 g_Whi[NSTATE * NSTATE];
__device__ __align__(16) _Float16 g_Wlo[NSTATE * NSTATE];
__device__ float    g_wb[NSTATE];
__device__ float    g_WmA[1024 * 512];
__device__ float    g_WmB[1024];
__device__ __align__(16) _Float16 g_Shi[2 * BATCH * NSTATE];
__device__ __align__(16) _Float16 g_Slo[2 * BATCH * NSTATE];
// [xcd*64]: island arrival counters; [512 + xcd*64]: registration counters
__device__ unsigned g_bar[1024];

// Forced local-L2 atomic RMW poll (returns pre-add value).  InstCombine
// cannot demote this to a (stale-L1-cacheable) load -- r12/r14 lessons.
__device__ __forceinline__ unsigned poll_rmw(unsigned* p) {
    unsigned old;
    asm volatile("global_atomic_add %0, %1, %2, off sc0\n\ts_waitcnt vmcnt(0)"
                 : "=&v"(old)
                 : "v"(p), "v"(0u)
                 : "memory");
    return old;
}

// Branch-free tanh: 1 - 2/(e^{2x}+1).  __expf -> v_exp_f32.  Exact limits:
// e=inf -> 1, e=0 -> -1.  |err| ~1e-7.
__device__ __forceinline__ float fast_tanh(float x) {
    float e = __expf(2.f * x);
    return 1.f - 2.f / (e + 1.f);
}

// W_mB[i] = sum_c W_m[i,c] * BT[c]
__global__ void prep_wmb(const float* __restrict__ Wm, const float* __restrict__ BT) {
    int row  = blockIdx.x * 4 + (threadIdx.x >> 6);
    int lane = threadIdx.x & 63;
    float s = 0.f;
    for (int c = lane; c < 512; c += 64) s += Wm[row * 512 + c] * BT[c];
    for (int o = 32; o; o >>= 1) s += __shfl_down(s, o);
    if (lane == 0) g_WmB[row] = s;
}

// W_mA = W_m @ (I + AT)
__global__ void prep_wma(const float* __restrict__ Wm, const float* __restrict__ AT) {
    __shared__ float As[32][33], Bs[32][33];
    int d0 = blockIdx.x * 32, i0 = blockIdx.y * 32;
    int tx = threadIdx.x & 31, ty = threadIdx.x >> 5;
    float acc[4];
#pragma unroll
    for (int r = 0; r < 4; ++r) acc[r] = Wm[(i0 + ty + 8 * r) * 512 + d0 + tx];
    for (int c0 = 0; c0 < 512; c0 += 32) {
#pragma unroll
        for (int r = 0; r < 4; ++r) {
            As[ty + 8 * r][tx] = Wm[(i0 + ty + 8 * r) * 512 + c0 + tx];
            Bs[ty + 8 * r][tx] = AT[(c0 + ty + 8 * r) * 512 + d0 + tx];
        }
        __syncthreads();
#pragma unroll
        for (int c = 0; c < 32; ++c)
#pragma unroll
            for (int r = 0; r < 4; ++r) acc[r] += As[ty + 8 * r][c] * Bs[c][tx];
        __syncthreads();
    }
#pragma unroll
    for (int r = 0; r < 4; ++r) g_WmA[(i0 + ty + 8 * r) * 512 + d0 + tx] = acc[r];
}

// Build W_full, f16 hi/lo (lo x2048), in slice-major fragment order:
// storage s = (((sl*48 + kt)*3 + nt)*64 + lane)*8 + j
//   n = sl*48 + nt*16 + (lane&15),  k = kt*32 + ((lane>>4)&3)*8 + j
__global__ void prep_wfull(const float* __restrict__ Wh, const float* __restrict__ AT,
                           const float* __restrict__ BT, const float* __restrict__ eh,
                           const float* __restrict__ em, const float* __restrict__ ex,
                           const float* __restrict__ Wx) {
    int s = blockIdx.x * 256 + threadIdx.x;     // [0, 1536*1536)
    int j8 = s & 7;
    int u = s >> 3;
    int lane = u & 63;
    u >>= 6;                                    // [0, 4608)
    int nt = u % 3; u /= 3;
    int kt = u % 48;
    int sl = u / 48;
    int n = sl * 48 + nt * 16 + (lane & 15);
    int k = kt * 32 + ((lane >> 4) & 3) * 8 + j8;

    float w;
    if (n < 1024) {
        if (k < 1024) w = Wh[n * 1024 + k] + g_WmB[n] * eh[k];
        else          w = g_WmA[n * 512 + (k - 1024)] + g_WmB[n] * em[k - 1024];
    } else {
        int c = n - 1024;
        if (k < 1024) w = BT[c] * eh[k];
        else {
            int d = k - 1024;
            w = ((c == d) ? 1.f : 0.f) + AT[c * 512 + d] + BT[c] * em[d];
        }
    }
    _Float16 hi = (_Float16)w;
    g_Whi[s] = hi;
    g_Wlo[s] = (_Float16)((w - (float)hi) * LO_SCALE);

    if (s < NSTATE) {
        float b = (s < 1024) ? (Wx[s] + ex[0] * g_WmB[s]) : (BT[s - 1024] * ex[0]);
        g_wb[s] = b;
    }
    if (s < 2 * BATCH * NSTATE) { g_Shi[s] = (_Float16)0.f; g_Slo[s] = (_Float16)0.f; }
    if (s < 1024) g_bar[s] = 0u;
}

__launch_bounds__(256, 1)
__global__ void lmu_persist(const float* __restrict__ inputs) {
    __shared__ half8  lwh[SLICE_H8];            // 147456 B: W_hi slice
    __shared__ float4 red[4 * 3 * 64];          // 12288 B: K-split partials
    __shared__ int    s_sl;

    const int tid = threadIdx.x;

    // ---- physical XCD id + rank registration (island = XCD) ----
    unsigned xcd;
    asm volatile("s_getreg_b32 %0, hwreg(HW_REG_XCC_ID)" : "=s"(xcd));
    xcd &= 7u;
    if (tid == 0) {
        unsigned rank = __hip_atomic_fetch_add(g_bar + 512 + xcd * 64, 1u,
                                               __ATOMIC_RELAXED,
                                               __HIP_MEMORY_SCOPE_WORKGROUP);
        s_sl = (int)(rank & 31u);               // column slice [0,32)
    }
    __syncthreads();
    const int isl = (int)xcd;                   // batch rows isl*16..+16
    const int sl  = s_sl;                       // cols sl*48..+48

    // stage W_hi slice -> LDS
    {
        const half8* src = (const half8*)g_Whi + (size_t)sl * SLICE_H8;
        for (int i = tid; i < SLICE_H8; i += 256) lwh[i] = src[i];
    }

    const int lane = tid & 63, wv = tid >> 6;
    const int quad = lane >> 4, l16 = lane & 15;
    const int rowA = isl * 16 + l16;            // A-frag batch row
    unsigned* cnt = g_bar + isl * 64;           // island arrival counter (local L2)

    // INTERLEAVED kt set: wave wv owns kt = wv + 4*ki, ki in [0,12).
    // ki>=8 <=> kt>=32 <=> m-columns (lo plane live) -- 4 per wave, balanced.

    // epilogue constants (wave wv<3 handles nt=wv)
    const int ncol = sl * 48 + wv * 16 + l16;
    const float wbv = (wv < 3) ? g_wb[ncol] : 0.f;
    const bool do_tanh = (sl * 48 + wv * 16) < 1024;   // h-granule: no lo store

    // ---- W_lo: FULLY register-resident (36 x half8 = 144 AGPRs), loaded once
    half8 wr[12 * 3];
    {
        const half8* wlo = (const half8*)g_Wlo + (size_t)sl * SLICE_H8;
#pragma unroll
        for (int ki = 0; ki < 12; ++ki)
#pragma unroll
            for (int nt = 0; nt < 3; ++nt)
                wr[ki * 3 + nt] = wlo[((wv + 4 * ki) * 3 + nt) * 64 + lane];
    }

    __syncthreads();

    int buf = 0;
    for (int t = 0; t < TSTEPS; ++t) {
        // PLAIN loads: producers share this XCD's L2 -> L2-local traffic
        const _Float16* shr =
            g_Shi + buf * BATCH * NSTATE + rowA * NSTATE + quad * 8;
        const _Float16* slr =
            g_Slo + buf * BATCH * NSTATE + rowA * NSTATE + quad * 8;

        // ---- PHASE 1: issue ALL state loads into registers (r25 lever).
        // 12 ah + 4 al, all independent 16B loads; sched_barrier(0) pins
        // them BEFORE the MFMA phase so the L2 round-trips pipeline
        // (first MFMA waits on the oldest load only), instead of each
        // load serializing against its consuming MFMA.
        half8 sa[12];
        half8 sb[4];
#pragma unroll
        for (int ki = 0; ki < 8; ++ki)
            sa[ki] = *(const half8*)(shr + (wv + 4 * ki) * 32);
#pragma unroll
        for (int ki = 8; ki < 12; ++ki) {
            sa[ki]     = *(const half8*)(shr + (wv + 4 * ki) * 32);
            sb[ki - 8] = *(const half8*)(slr + (wv + 4 * ki) * 32);
        }
        __builtin_amdgcn_sched_barrier(0);

        // ---- PHASE 2: MFMA over the staged registers + LDS W_hi ----
        floatx4 aA[3], aB[3], aC[3];
#pragma unroll
        for (int q = 0; q < 3; ++q) { aA[q] = (floatx4)0.f; aB[q] = (floatx4)0.f; aC[q] = (floatx4)0.f; }

#pragma unroll
        for (int ki = 0; ki < 12; ++ki) {
            const int kt = wv + 4 * ki;
#pragma unroll
            for (int nt = 0; nt < 3; ++nt) {
                half8 bh = lwh[(kt * 3 + nt) * 64 + lane];
                aA[nt] = __builtin_amdgcn_mfma_f32_16x16x32_f16(sa[ki], bh, aA[nt], 0, 0, 0);
                if (ki >= 8)
                    aB[nt] = __builtin_amdgcn_mfma_f32_16x16x32_f16(sb[ki - 8], bh, aB[nt], 0, 0, 0);
                aC[nt] = __builtin_amdgcn_mfma_f32_16x16x32_f16(sa[ki], wr[ki * 3 + nt], aC[nt], 0, 0, 0);
            }
        }

        // K-split partials -> LDS
#pragma unroll
        for (int nt = 0; nt < 3; ++nt) {
            floatx4 P = aA[nt] + (aB[nt] + aC[nt]) * LO_INV;
            red[(wv * 3 + nt) * 64 + lane] = float4{P[0], P[1], P[2], P[3]};
        }
        __syncthreads();

        // waves 0-2: reduce + bias + activation + hi/lo split + PLAIN store
        const int nbuf = buf ^ 1;
        if (wv < 3) {
            float4 v0 = red[(0 * 3 + wv) * 64 + lane];
            float4 v1 = red[(1 * 3 + wv) * 64 + lane];
            float4 v2 = red[(2 * 3 + wv) * 64 + lane];
            float4 v3 = red[(3 * 3 + wv) * 64 + lane];
            float vr4[4] = {v0.x + v1.x + v2.x + v3.x, v0.y + v1.y + v2.y + v3.y,
                            v0.z + v1.z + v2.z + v3.z, v0.w + v1.w + v2.w + v3.w};
            _Float16* dh = g_Shi + nbuf * BATCH * NSTATE;
            _Float16* dl = g_Slo + nbuf * BATCH * NSTATE;
            const float* xt = inputs + t * BATCH + isl * 16 + quad * 4;
            if (do_tanh) {
                // h-granule: f16 hi only, no lo store
#pragma unroll
                for (int r = 0; r < 4; ++r) {
                    int b = isl * 16 + quad * 4 + r;
                    float v = fast_tanh(vr4[r] + xt[r] * wbv);
                    dh[b * NSTATE + ncol] = (_Float16)v;
                }
            } else {
                // m-granule: keep hi/lo pair
#pragma unroll
                for (int r = 0; r < 4; ++r) {
                    int b = isl * 16 + quad * 4 + r;
                    float v = vr4[r] + xt[r] * wbv;
                    _Float16 hi = (_Float16)v;
                    dh[b * NSTATE + ncol] = hi;
                    dl[b * NSTATE + ncol] = (_Float16)((v - (float)hi) * LO_SCALE);
                }
            }
        }

        // drain stores (syncthreads emits vmcnt(0)), then flat LOCAL-L2
        // barrier: arrival = wg-scope RMW(+1); poll = asm RMW(+0) sc0 with
        // s_sleep(4) backoff (r24: neutral but harmless -- keeps the
        // counter line's TCC queue near-empty).
        __builtin_amdgcn_fence(__ATOMIC_RELEASE, "workgroup");
        __syncthreads();
        if (tid == 0) {
            __hip_atomic_fetch_add(cnt, 1u, __ATOMIC_RELAXED,
                                   __HIP_MEMORY_SCOPE_WORKGROUP);
            const unsigned target = (unsigned)ISL_WGS * (unsigned)(t + 1);
            int spin = 0;
            while (poll_rmw(cnt) < target) {
                __builtin_amdgcn_s_sleep(4);    // ~256 cy low-power backoff
                if (++spin > (1 << 18)) break;  // deadman: no hang
            }
        }
        __syncthreads();
        // CU-local L1 invalidate only (L2 holds the island's fresh state)
        asm volatile("buffer_inv\n\ts_waitcnt vmcnt(0)" ::: "memory");
        __builtin_amdgcn_fence(__ATOMIC_ACQUIRE, "workgroup");
        buf = nbuf;
    }
}

// logits + softmax: one WG per batch row (final state in plane 0: 784 even;
// dispatch boundary flushes every XCD's L2 so state is globally visible).
// h is f16 HI-ONLY (cols < 1024 feed the dense layer).
__global__ void lmu_out(const float* __restrict__ Wd, const float* __restrict__ bd,
                        float* __restrict__ out) {
    __shared__ float red[272];
    int b = blockIdx.x;
    const _Float16* sh = g_Shi + b * NSTATE;
    int tid = threadIdx.x;
    int c = tid & 15, chunk = tid >> 4;
    float part = 0.f;
    if (c < 10) {
        for (int i = chunk * 64; i < chunk * 64 + 64; ++i)
            part += (float)sh[i] * Wd[c * 1024 + i];
    }
    red[chunk * 16 + c] = part;
    __syncthreads();
    if (tid < 10) {
        float lg = bd[tid];
        for (int q = 0; q < 16; ++q) lg += red[q * 16 + tid];
        red[256 + tid] = lg;
    }
    __syncthreads();
    if (tid < 10) {
        float mx = red[256];
        for (int q = 1; q < 10; ++q) mx = fmaxf(mx, red[256 + q]);
        float sm = 0.f;
        for (int q = 0; q < 10; ++q) sm += expf(red[256 + q] - mx);
        out[b * 10 + tid] = expf(red[256 + tid] - mx) / sm;
    }
}

extern "C" void kernel_launch(void* const* d_in, const int* in_sizes, int n_in,
                              void* d_out, int out_size, void* d_ws, size_t ws_size,
                              hipStream_t stream) {
    const float* inputs = (const float*)d_in[0];
    const float* e_x    = (const float*)d_in[1];
    const float* e_h    = (const float*)d_in[2];
    const float* e_m    = (const float*)d_in[3];
    const float* W_x    = (const float*)d_in[4];
    const float* W_h    = (const float*)d_in[5];
    const float* W_m    = (const float*)d_in[6];
    const float* AT     = (const float*)d_in[7];
    const float* BT     = (const float*)d_in[8];
    const float* W_d    = (const float*)d_in[9];
    const float* b_d    = (const float*)d_in[10];
    (void)d_ws; (void)ws_size; (void)in_sizes; (void)n_in;

    prep_wmb<<<256, 256, 0, stream>>>(W_m, BT);
    prep_wma<<<dim3(16, 32), 256, 0, stream>>>(W_m, AT);
    prep_wfull<<<9216, 256, 0, stream>>>(W_h, AT, BT, e_h, e_m, e_x, W_x);

    lmu_persist<<<256, 256, 0, stream>>>(inputs);

    lmu_out<<<128, 256, 0, stream>>>(W_d, b_d, (float*)d_out);
}